// Round 6
// baseline (1265.421 us; speedup 1.0000x reference)
//
#include <hip/hip_runtime.h>
#include <hip/hip_bf16.h>
#include <stdint.h>
#include <stddef.h>

typedef __attribute__((ext_vector_type(8))) short short8;
typedef __attribute__((ext_vector_type(4))) float f32x4;

#define NB 2048
#define HD 512
#define SD 256

__device__ __forceinline__ short f2bf(float x) {
  __hip_bfloat16 h = __float2bfloat16(x);
  return *reinterpret_cast<short*>(&h);
}

__device__ __forceinline__ float fast_tanh(float x) {
  x = fminf(fmaxf(x, -15.f), 15.f);
  float e = __expf(2.f * x);
  return __fdividef(e - 1.f, e + 1.f);
}

// ---- Wtb[kb][j][kk] = bf16(W[kb*32+kk][j]) : k-blocked transposed layout ----
__global__ __launch_bounds__(256) void wconv_kernel(const float* __restrict__ W,
                                                    short* __restrict__ Wtb) {
  __shared__ float tile[32][33];
  const int bx = blockIdx.x;
  const int tk0 = (bx & 15) * 32;
  const int tj0 = (bx >> 4) * 32;
  const int lx = threadIdx.x & 31;
  const int ly = threadIdx.x >> 5;
  for (int r = 0; r < 4; ++r) {
    int yy = ly + r * 8;
    tile[yy][lx] = W[(size_t)(tk0 + yy) * HD + tj0 + lx];
  }
  __syncthreads();
  const int kb = tk0 >> 5;
  for (int r = 0; r < 4; ++r) {
    int yy = ly + r * 8;
    Wtb[(size_t)kb * (HD * 32) + (size_t)(tj0 + yy) * 32 + lx] = f2bf(tile[lx][yy]);
  }
}

// ---- hst[n'][s][h] = bf16(hs[nbase+n'][h][s]) : transpose + convert ----
// 64x64 tiles through LDS (stride 65: 2-way banks both phases = free).
__global__ __launch_bounds__(256) void tconv_kernel(const float* __restrict__ hs,
                                                    short* __restrict__ hst,
                                                    int nbase) {
  __shared__ float tile[64][65];
  const int bx = blockIdx.x;
  const int nl = bx >> 5;                 // local n within chunk
  const int n = nbase + nl;
  const int h0 = ((bx >> 2) & 7) * 64;
  const int s0 = (bx & 3) * 64;
  const int t = threadIdx.x;

  // load: 64 h-rows x 64 s floats (float4 global, scalar LDS writes)
  const int lh = t >> 2;                  // 0..63
  const int lq = t & 3;                   // 0..3
  const float* src = hs + (size_t)n * (HD * SD) + (size_t)(h0 + lh) * SD + s0;
  #pragma unroll
  for (int r = 0; r < 4; ++r) {
    const int q = lq + r * 4;             // float4 index 0..15
    float4 v = *(const float4*)(src + q * 4);
    tile[lh][q * 4 + 0] = v.x;
    tile[lh][q * 4 + 1] = v.y;
    tile[lh][q * 4 + 2] = v.z;
    tile[lh][q * 4 + 3] = v.w;
  }
  __syncthreads();

  // store: 64 s-rows x 64 h bf16 (column reads, dwordx4 global writes)
  const int ls = t >> 2;                  // 0..63
  const int lo = t & 3;                   // 0..3
  short* dst = hst + (size_t)nl * (SD * HD) + (size_t)(s0 + ls) * HD + h0;
  #pragma unroll
  for (int r = 0; r < 2; ++r) {
    const int oct = lo + r * 4;           // 0..7
    short8 pk;
    #pragma unroll
    for (int e = 0; e < 8; ++e)
      pk[e] = f2bf(tile[oct * 8 + e][ls]);
    *(short8*)(dst + oct * 8) = pk;
  }
}

// ---- alignment[n][s] = sum_j tanh( sum_k hs[n,k,s]*W[k,j] + b[j] ) * c[j] ----
// FAST PATH: A from pre-transposed bf16 hst -> one dwordx4 per fragment, no
// pack VALU, no LDS, no k-loop barriers. Explicit 2-deep register double
// buffer (named bufs, static indices); MFMA consumes loads directly so the
// compiler emits counted vmcnt waits.
__global__ void __launch_bounds__(256, 2)
align_fast(const short* __restrict__ hst, const short* __restrict__ Wtb,
           const float* __restrict__ bias, const float* __restrict__ ctx,
           float* __restrict__ align_out, int nbase)
{
  __shared__ float abuf[64];

  const int tid = threadIdx.x;
  const int nl = blockIdx.x >> 2;         // local n within chunk
  const int n = nbase + nl;
  const int s0 = (blockIdx.x & 3) * 64;
  const int lane = tid & 63;
  const int wid = tid >> 6;
  const int l15 = lane & 15;
  const int lg = lane >> 4;
  const int jb = wid * 128;

  if (tid < 64) abuf[tid] = 0.f;
  __syncthreads();

  // A (B-operand): lane reads hst[nl][s0 + i*16 + l15][kt*32 + lg*8 .. +8]
  const short* aBase = hst + (size_t)nl * (SD * HD) + (size_t)(s0 + l15) * HD + lg * 8;
  // W (A-operand): lane reads Wtb[kt][jb + p*16 + l15][lg*8 .. +8]
  const short* wBase = Wtb + (size_t)(jb + l15) * 32 + lg * 8;

  f32x4 acc[4][8];
  #pragma unroll
  for (int i = 0; i < 4; ++i)
    #pragma unroll
    for (int p = 0; p < 8; ++p)
      acc[i][p] = (f32x4){0.f, 0.f, 0.f, 0.f};

  short8 afA[4], wfA[8], afB[4], wfB[8];
  // prologue: kt=0 into A-bufs
  #pragma unroll
  for (int i = 0; i < 4; ++i) afA[i] = *(const short8*)(aBase + i * 16 * HD);
  #pragma unroll
  for (int p = 0; p < 8; ++p) wfA[p] = *(const short8*)(wBase + p * (16 * 32));

  for (int kt = 0; kt < 16; kt += 2) {
    // prefetch kt+1 into B-bufs (12 loads, stay in flight over MFMA(A))
    {
      const short* ak = aBase + (kt + 1) * 32;
      #pragma unroll
      for (int i = 0; i < 4; ++i) afB[i] = *(const short8*)(ak + i * 16 * HD);
      const short* wk = wBase + (size_t)(kt + 1) * (HD * 32);
      #pragma unroll
      for (int p = 0; p < 8; ++p) wfB[p] = *(const short8*)(wk + p * (16 * 32));
    }
    // MFMA on A-bufs
    #pragma unroll
    for (int i = 0; i < 4; ++i)
      #pragma unroll
      for (int p = 0; p < 8; ++p)
        acc[i][p] = __builtin_amdgcn_mfma_f32_16x16x32_bf16(wfA[p], afA[i], acc[i][p], 0, 0, 0);
    // prefetch kt+2 into A-bufs
    if (kt < 14) {
      const short* ak = aBase + (kt + 2) * 32;
      #pragma unroll
      for (int i = 0; i < 4; ++i) afA[i] = *(const short8*)(ak + i * 16 * HD);
      const short* wk = wBase + (size_t)(kt + 2) * (HD * 32);
      #pragma unroll
      for (int p = 0; p < 8; ++p) wfA[p] = *(const short8*)(wk + p * (16 * 32));
    }
    // MFMA on B-bufs
    #pragma unroll
    for (int i = 0; i < 4; ++i)
      #pragma unroll
      for (int p = 0; p < 8; ++p)
        acc[i][p] = __builtin_amdgcn_mfma_f32_16x16x32_bf16(wfB[p], afB[i], acc[i][p], 0, 0, 0);
  }

  // epilogue: D rows = j (lg*4 + r per fragment), cols = s (l15).
  float part[4] = {0.f, 0.f, 0.f, 0.f};
  #pragma unroll
  for (int p = 0; p < 8; ++p) {
    const int j = jb + p * 16 + lg * 4;
    f32x4 bv = *(const f32x4*)(bias + j);
    f32x4 cv = *(const f32x4*)(ctx + j);
    #pragma unroll
    for (int i = 0; i < 4; ++i)
      #pragma unroll
      for (int r = 0; r < 4; ++r)
        part[i] += fast_tanh(acc[i][p][r] + bv[r]) * cv[r];
  }
  #pragma unroll
  for (int i = 0; i < 4; ++i) {
    part[i] += __shfl_xor(part[i], 16);
    part[i] += __shfl_xor(part[i], 32);
  }
  if (lg == 0) {
    #pragma unroll
    for (int i = 0; i < 4; ++i)
      atomicAdd(&abuf[i * 16 + l15], part[i]);
  }
  __syncthreads();
  if (tid < 64) align_out[(size_t)n * SD + s0 + tid] = abuf[tid];
}

// ---- FALLBACK align (round-4 structure): direct fp32 A loads + pack ----
__global__ void __launch_bounds__(256, 2)
align_fallback(const float* __restrict__ hs, const short* __restrict__ Wtb,
               const float* __restrict__ bias, const float* __restrict__ ctx,
               float* __restrict__ align_out)
{
  __shared__ float abuf[64];
  const int tid = threadIdx.x;
  const int n = blockIdx.x >> 2;
  const int s0 = (blockIdx.x & 3) * 64;
  const int lane = tid & 63;
  const int wid = tid >> 6;
  const int l15 = lane & 15;
  const int lg = lane >> 4;
  const int jb = wid * 128;

  if (tid < 64) abuf[tid] = 0.f;
  __syncthreads();

  const float* hsA = hs + (size_t)n * (HD * SD) + s0 + l15 + (size_t)(lg * 8) * SD;
  const short* wbase = Wtb + (size_t)(jb + l15) * 32 + lg * 8;

  f32x4 acc[4][8];
  #pragma unroll
  for (int i = 0; i < 4; ++i)
    #pragma unroll
    for (int p = 0; p < 8; ++p)
      acc[i][p] = (f32x4){0.f, 0.f, 0.f, 0.f};

  for (int kt = 0; kt < 16; ++kt) {
    short8 wf[8];
    const short* wk = wbase + (size_t)kt * (HD * 32);
    #pragma unroll
    for (int p = 0; p < 8; ++p)
      wf[p] = *(const short8*)(wk + p * (16 * 32));

    short8 af[4];
    const float* ak = hsA + (size_t)(kt * 32) * SD;
    #pragma unroll
    for (int i = 0; i < 4; ++i) {
      float v[8];
      #pragma unroll
      for (int e = 0; e < 8; ++e)
        v[e] = ak[(size_t)e * SD + i * 16];
      short8 pk;
      #pragma unroll
      for (int e = 0; e < 8; ++e) pk[e] = f2bf(v[e]);
      af[i] = pk;
    }

    #pragma unroll
    for (int i = 0; i < 4; ++i)
      #pragma unroll
      for (int p = 0; p < 8; ++p)
        acc[i][p] = __builtin_amdgcn_mfma_f32_16x16x32_bf16(wf[p], af[i], acc[i][p], 0, 0, 0);
  }

  float part[4] = {0.f, 0.f, 0.f, 0.f};
  #pragma unroll
  for (int p = 0; p < 8; ++p) {
    const int j = jb + p * 16 + lg * 4;
    f32x4 bv = *(const f32x4*)(bias + j);
    f32x4 cv = *(const f32x4*)(ctx + j);
    #pragma unroll
    for (int i = 0; i < 4; ++i)
      #pragma unroll
      for (int r = 0; r < 4; ++r)
        part[i] += fast_tanh(acc[i][p][r] + bv[r]) * cv[r];
  }
  #pragma unroll
  for (int i = 0; i < 4; ++i) {
    part[i] += __shfl_xor(part[i], 16);
    part[i] += __shfl_xor(part[i], 32);
  }
  if (lg == 0) {
    #pragma unroll
    for (int i = 0; i < 4; ++i)
      atomicAdd(&abuf[i * 16 + l15], part[i]);
  }
  __syncthreads();
  if (tid < 64) align_out[(size_t)n * SD + s0 + tid] = abuf[tid];
}

// ---- softmax over s + context[n,h] = sum_s attn[s]*hs[n,h,s] ----
__global__ __launch_bounds__(256) void ctx_kernel(const float* __restrict__ hs,
                                                  const float* __restrict__ align_in,
                                                  float* __restrict__ out)
{
  __shared__ __align__(16) float attn_s[256];
  __shared__ float red[8];
  const int n = blockIdx.x;
  const int t = threadIdx.x;
  const int lane = t & 63, wid = t >> 6;

  float a = align_in[(size_t)n * 256 + t];
  float m = a;
  #pragma unroll
  for (int off = 32; off; off >>= 1) m = fmaxf(m, __shfl_xor(m, off));
  if (lane == 0) red[wid] = m;
  __syncthreads();
  m = fmaxf(fmaxf(red[0], red[1]), fmaxf(red[2], red[3]));
  float e = __expf(a - m);
  float s = e;
  #pragma unroll
  for (int off = 32; off; off >>= 1) s += __shfl_xor(s, off);
  if (lane == 0) red[4 + wid] = s;
  __syncthreads();
  s = red[4] + red[5] + red[6] + red[7];
  attn_s[t] = e / s;
  __syncthreads();

  const int grp = t & 7;
  const int hrow = t >> 3;
  float av[32];
  #pragma unroll
  for (int u = 0; u < 8; ++u) {
    float4 v = *(const float4*)&attn_s[grp * 32 + u * 4];
    av[4*u+0] = v.x; av[4*u+1] = v.y; av[4*u+2] = v.z; av[4*u+3] = v.w;
  }
  const float* hb = hs + (size_t)n * (HD * SD) + grp * 32;
  for (int it = 0; it < 16; ++it) {
    const int h = it * 32 + hrow;
    const float4* p = (const float4*)(hb + (size_t)h * SD);
    float acc = 0.f;
    #pragma unroll
    for (int u = 0; u < 8; ++u) {
      float4 v = p[u];
      acc += av[4*u+0]*v.x + av[4*u+1]*v.y + av[4*u+2]*v.z + av[4*u+3]*v.w;
    }
    acc += __shfl_xor(acc, 1);
    acc += __shfl_xor(acc, 2);
    acc += __shfl_xor(acc, 4);
    if (grp == 0) out[(size_t)n * HD + h] = acc;
  }
}

extern "C" void kernel_launch(void* const* d_in, const int* in_sizes, int n_in,
                              void* d_out, int out_size, void* d_ws, size_t ws_size,
                              hipStream_t stream) {
  (void)in_sizes; (void)n_in; (void)out_size;
  const float* hs = (const float*)d_in[0];
  const float* W  = (const float*)d_in[1];
  const float* b  = (const float*)d_in[2];
  const float* c  = (const float*)d_in[3];
  float* out = (float*)d_out;

  const size_t OFF_ALIGN = 0;                                   // 2 MB
  const size_t OFF_WTB   = (size_t)NB * SD * 4;                 // +512 KB
  const size_t OFF_HST   = OFF_WTB + (size_t)16 * HD * 32 * 2;  // hst after
  const size_t HST_FULL  = (size_t)NB * SD * HD * 2;            // 512 MB
  const size_t HST_CHUNK = HST_FULL / 8;                        // 64 MB

  float* align_ws = (float*)((char*)d_ws + OFF_ALIGN);
  short* Wtb = (short*)((char*)d_ws + OFF_WTB);
  short* hst = (short*)((char*)d_ws + OFF_HST);

  wconv_kernel<<<256, 256, 0, stream>>>(W, Wtb);

  if (ws_size >= OFF_HST + HST_FULL) {
    // full path: one transpose pass, one align pass
    tconv_kernel<<<NB * 32, 256, 0, stream>>>(hs, hst, 0);
    align_fast<<<NB * 4, 256, 0, stream>>>(hst, Wtb, b, c, align_ws, 0);
  } else if (ws_size >= OFF_HST + HST_CHUNK) {
    // chunked path: reuse a 64 MB hst buffer, 8 chunks of 256 n
    for (int chunk = 0; chunk < 8; ++chunk) {
      const int nbase = chunk * (NB / 8);
      tconv_kernel<<<(NB / 8) * 32, 256, 0, stream>>>(hs, hst, nbase);
      align_fast<<<(NB / 8) * 4, 256, 0, stream>>>(hst, Wtb, b, c, align_ws, nbase);
    }
  } else {
    // fallback: round-4 structure, needs only 2.5 MB
    align_fallback<<<NB * 4, 256, 0, stream>>>(hs, Wtb, b, c, align_ws);
  }

  ctx_kernel<<<NB, 256, 0, stream>>>(hs, align_ws, out);
}

// Round 7
// 862.581 us; speedup vs baseline: 1.4670x; 1.4670x over previous
//
#include <hip/hip_runtime.h>
#include <hip/hip_bf16.h>
#include <stdint.h>
#include <stddef.h>

typedef __attribute__((ext_vector_type(8))) short short8;
typedef __attribute__((ext_vector_type(4))) float f32x4;

#define NB 2048
#define HD 512
#define SD 256
#define A_STR 36   // shorts per A-tile row (32 k + 4 pad) -> 72B stride

__device__ __forceinline__ short f2bf(float x) {
  __hip_bfloat16 h = __float2bfloat16(x);
  return *reinterpret_cast<short*>(&h);
}

__device__ __forceinline__ float fast_tanh(float x) {
  x = fminf(fmaxf(x, -15.f), 15.f);
  float e = __expf(2.f * x);
  return __fdividef(e - 1.f, e + 1.f);
}

// ---- Wtb[kb][j][kk] = bf16(W[kb*32+kk][j]) : k-blocked transposed layout ----
__global__ __launch_bounds__(256) void wconv_kernel(const float* __restrict__ W,
                                                    short* __restrict__ Wtb) {
  __shared__ float tile[32][33];
  const int bx = blockIdx.x;
  const int tk0 = (bx & 15) * 32;
  const int tj0 = (bx >> 4) * 32;
  const int lx = threadIdx.x & 31;
  const int ly = threadIdx.x >> 5;
  for (int r = 0; r < 4; ++r) {
    int yy = ly + r * 8;
    tile[yy][lx] = W[(size_t)(tk0 + yy) * HD + tj0 + lx];
  }
  __syncthreads();
  const int kb = tk0 >> 5;
  for (int r = 0; r < 4; ++r) {
    int yy = ly + r * 8;
    Wtb[(size_t)kb * (HD * 32) + (size_t)(tj0 + yy) * 32 + lx] = f2bf(tile[lx][yy]);
  }
}

// ---- fused: align (MFMA) + softmax + context, one block per n ----
// 512 threads = 8 waves (2 s-halves x 4 j-quarters), wave tile 64s x 128j.
// Phase 1 (x2 s-halves): A-tile [128s][32k] bf16 double-buffered in LDS
// (pack amortized: each staged element feeds 32 MFMAs); W fragments straight
// from L2-resident Wtb, register double-buffered, issued BEFORE the MFMA
// cluster; the vmcnt drain for staging sits AFTER the MFMAs so HBM/L2
// latency hides under compute. Phase 2: softmax in LDS, context re-reads
// hs[n] (512 KB, L3-resident: 256 blocks x 512 KB = 128 MB < 256 MB L3).
__global__ void __launch_bounds__(512, 2)
fused_kernel(const float* __restrict__ hs, const short* __restrict__ Wtb,
             const float* __restrict__ bias, const float* __restrict__ ctxv,
             float* __restrict__ out)
{
  __shared__ short As[2][128 * A_STR];       // 18 KB
  __shared__ float abuf[SD];
  __shared__ __align__(16) float attn_s[SD];
  __shared__ float red[16];

  const int tid = threadIdx.x;
  const int n = blockIdx.x;
  const float* hsn = hs + (size_t)n * (HD * SD);

  if (tid < SD) abuf[tid] = 0.f;

  const int lane = tid & 63;
  const int wid = tid >> 6;      // 0..7
  const int wm = wid >> 2;       // 0..1 : 64-s half of the 128-s tile
  const int wj = wid & 3;        // 0..3 : 128-j quarter
  const int l15 = lane & 15;
  const int lg = lane >> 4;

  // staging map: thread loads 8 consecutive k at one s (coalesced 256B/wave)
  const int st_s = tid & 127;
  const int st_ko = tid >> 7;    // k-octet 0..3

  // W per-lane fragment base: row j = wj*128 + p*16 + l15, k-octet lg
  const short* wBase = Wtb + (size_t)(wj * 128 + l15) * 32 + lg * 8;

  // ================= PHASE 1: alignment =================
  for (int sh = 0; sh < 2; ++sh) {
    const int s0 = sh * 128;
    const float* hss = hsn + s0;

    // prologue: stage kt=0 into As[0]
    {
      const float* src = hss + (size_t)(st_ko * 8) * SD + st_s;
      short8 pk;
      #pragma unroll
      for (int e = 0; e < 8; ++e) pk[e] = f2bf(src[(size_t)e * SD]);
      *(short8*)&As[0][st_s * A_STR + st_ko * 8] = pk;
    }
    // prologue: W fragments for kt=0
    short8 wfA[8], wfB[8];
    #pragma unroll
    for (int p = 0; p < 8; ++p) wfA[p] = *(const short8*)(wBase + p * (16 * 32));

    __syncthreads();

    f32x4 acc[4][8];
    #pragma unroll
    for (int i = 0; i < 4; ++i)
      #pragma unroll
      for (int p = 0; p < 8; ++p)
        acc[i][p] = (f32x4){0.f, 0.f, 0.f, 0.f};

    #pragma unroll 2
    for (int kt = 0; kt < 16; ++kt) {
      const int cur = kt & 1;

      // A fragments from LDS
      short8 af[4];
      #pragma unroll
      for (int i = 0; i < 4; ++i)
        af[i] = *(const short8*)&As[cur][(wm * 64 + i * 16 + l15) * A_STR + lg * 8];

      // issue NEXT step's W (into the other reg buffer) and raw-A loads
      float ar[8];
      if (kt < 15) {
        const short* wk = wBase + (size_t)(kt + 1) * (HD * 32);
        if (cur == 0) {
          #pragma unroll
          for (int p = 0; p < 8; ++p) wfB[p] = *(const short8*)(wk + p * (16 * 32));
        } else {
          #pragma unroll
          for (int p = 0; p < 8; ++p) wfA[p] = *(const short8*)(wk + p * (16 * 32));
        }
        const float* src = hss + (size_t)((kt + 1) * 32 + st_ko * 8) * SD + st_s;
        #pragma unroll
        for (int e = 0; e < 8; ++e) ar[e] = src[(size_t)e * SD];
      }

      // MFMA cluster on the CURRENT W reg-buffer (already resident -> no
      // vmem wait; the 16 just-issued loads stay in flight underneath)
      if (cur == 0) {
        #pragma unroll
        for (int i = 0; i < 4; ++i)
          #pragma unroll
          for (int p = 0; p < 8; ++p)
            acc[i][p] = __builtin_amdgcn_mfma_f32_16x16x32_bf16(wfA[p], af[i], acc[i][p], 0, 0, 0);
      } else {
        #pragma unroll
        for (int i = 0; i < 4; ++i)
          #pragma unroll
          for (int p = 0; p < 8; ++p)
            acc[i][p] = __builtin_amdgcn_mfma_f32_16x16x32_bf16(wfB[p], af[i], acc[i][p], 0, 0, 0);
      }

      // drain + pack + LDS-write the prefetched A, then step barrier
      if (kt < 15) {
        short8 pk;
        #pragma unroll
        for (int e = 0; e < 8; ++e) pk[e] = f2bf(ar[e]);
        *(short8*)&As[cur ^ 1][st_s * A_STR + st_ko * 8] = pk;
      }
      __syncthreads();
    }

    // epilogue: D rows = j (lg*4 + r), cols = s (l15). tanh + *c, reduce j.
    float part[4] = {0.f, 0.f, 0.f, 0.f};
    #pragma unroll
    for (int p = 0; p < 8; ++p) {
      const int j = wj * 128 + p * 16 + lg * 4;
      f32x4 bv = *(const f32x4*)(bias + j);
      f32x4 cv = *(const f32x4*)(ctxv + j);
      #pragma unroll
      for (int i = 0; i < 4; ++i)
        #pragma unroll
        for (int r = 0; r < 4; ++r)
          part[i] += fast_tanh(acc[i][p][r] + bv[r]) * cv[r];
    }
    #pragma unroll
    for (int i = 0; i < 4; ++i) {
      part[i] += __shfl_xor(part[i], 16);
      part[i] += __shfl_xor(part[i], 32);
    }
    if (lg == 0) {
      #pragma unroll
      for (int i = 0; i < 4; ++i)
        atomicAdd(&abuf[s0 + wm * 64 + i * 16 + l15], part[i]);
    }
    __syncthreads();   // abuf done for this half; safe to re-stage As next half
  }

  // ================= PHASE 2: softmax =================
  {
    float a = (tid < SD) ? abuf[tid] : -1e30f;
    float m = a;
    #pragma unroll
    for (int off = 32; off; off >>= 1) m = fmaxf(m, __shfl_xor(m, off));
    if (lane == 0) red[wid] = m;
    __syncthreads();
    m = red[0];
    #pragma unroll
    for (int w = 1; w < 8; ++w) m = fmaxf(m, red[w]);
    float e = (tid < SD) ? __expf(a - m) : 0.f;
    float s = e;
    #pragma unroll
    for (int off = 32; off; off >>= 1) s += __shfl_xor(s, off);
    if (lane == 0) red[8 + wid] = s;
    __syncthreads();
    s = red[8];
    #pragma unroll
    for (int w = 1; w < 8; ++w) s += red[8 + w];
    if (tid < SD) attn_s[tid] = e / s;
    __syncthreads();
  }

  // ================= PHASE 3: context (hs[n] from L3) =================
  {
    const int grp = tid & 7;      // s-chunk of 32
    const int hrow = tid >> 3;    // 0..63
    float av[32];
    #pragma unroll
    for (int u = 0; u < 8; ++u) {
      float4 v = *(const float4*)&attn_s[grp * 32 + u * 4];
      av[4*u+0] = v.x; av[4*u+1] = v.y; av[4*u+2] = v.z; av[4*u+3] = v.w;
    }
    const float* hb = hsn + grp * 32;
    #pragma unroll
    for (int it = 0; it < 8; ++it) {
      const int h = it * 64 + hrow;
      const float4* p = (const float4*)(hb + (size_t)h * SD);
      float acc = 0.f;
      #pragma unroll
      for (int u = 0; u < 8; ++u) {
        float4 v = p[u];
        acc += av[4*u+0]*v.x + av[4*u+1]*v.y + av[4*u+2]*v.z + av[4*u+3]*v.w;
      }
      acc += __shfl_xor(acc, 1);
      acc += __shfl_xor(acc, 2);
      acc += __shfl_xor(acc, 4);
      if (grp == 0) out[(size_t)n * HD + h] = acc;
    }
  }
}

extern "C" void kernel_launch(void* const* d_in, const int* in_sizes, int n_in,
                              void* d_out, int out_size, void* d_ws, size_t ws_size,
                              hipStream_t stream) {
  (void)in_sizes; (void)n_in; (void)out_size; (void)ws_size;
  const float* hs = (const float*)d_in[0];
  const float* W  = (const float*)d_in[1];
  const float* b  = (const float*)d_in[2];
  const float* c  = (const float*)d_in[3];
  float* out = (float*)d_out;

  short* Wtb = (short*)d_ws;   // 512 KB

  wconv_kernel<<<256, 256, 0, stream>>>(W, Wtb);
  fused_kernel<<<NB, 512, 0, stream>>>(hs, Wtb, b, c, out);
}